// Round 10
// baseline (754.169 us; speedup 1.0000x reference)
//
#include <hip/hip_runtime.h>
#include <hip/hip_bf16.h>

// RolePositionBiasedAttention: B=16384, N=10, D=256, H=8, DH=32
// prep_wt -> fused_qkv_attn (40-row blocks, 4 blocks/CU: QKV strip GEMM + VALU attn)
//         -> gemm_wo2
// r2 structure; occupancy doubled (16 waves/CU), 2 barriers/pass, no reg spill.

typedef __attribute__((ext_vector_type(8))) short bf16x8;
typedef __attribute__((ext_vector_type(4))) float f32x4;

__device__ __forceinline__ unsigned short f2bf(float f) {
  union { __hip_bfloat16 h; unsigned short u; } cv;
  cv.h = __float2bfloat16(f);
  return cv.u;
}
__device__ __forceinline__ float bflo(unsigned int u) { return __uint_as_float(u << 16); }
__device__ __forceinline__ float bfhi(unsigned int u) { return __uint_as_float(u & 0xffff0000u); }

// ---------------- prep: WT[w][n][k] = bf16(W[k][n]), w in {Q,K,V,O} ----------------
__global__ void prep_wt_kernel(const float* __restrict__ WQ, const float* __restrict__ WK,
                               const float* __restrict__ WV, const float* __restrict__ WO,
                               __hip_bfloat16* __restrict__ wt) {
  const int k = blockIdx.x;      // 0..255
  const int n = threadIdx.x;     // 0..255
  wt[0 * 65536 + n * 256 + k] = __float2bfloat16(WQ[k * 256 + n]);
  wt[1 * 65536 + n * 256 + k] = __float2bfloat16(WK[k * 256 + n]);
  wt[2 * 65536 + n * 256 + k] = __float2bfloat16(WV[k * 256 + n]);
  wt[3 * 65536 + n * 256 + k] = __float2bfloat16(WO[k * 256 + n]);
}

// LDS layout (bytes) — total 40,624 <= 40,960 -> 4 blocks/CU:
#define AS_OFF 0        // [48][512] Z bf16 (rows 40..47 garbage pad; their C rows discarded)
#define SP_OFF 24576    // [40][400] strip: q cols 0..63 | k 64..127 | v 128..191, swizzled
#define RL_OFF 40576    // 48 roles (u8)
#define LDS_SZ 40624

__global__ __launch_bounds__(256, 4) void fused_qkv_attn_kernel(
    const float* __restrict__ Z, const __hip_bfloat16* __restrict__ wt,
    const int* __restrict__ roles, const float* __restrict__ Bp,
    __hip_bfloat16* __restrict__ attn_out)
{
  __shared__ __align__(16) char lds[LDS_SZ];
  unsigned char* rl = (unsigned char*)(lds + RL_OFF);

  const int t = threadIdx.x;
  const int lane = t & 63;
  const int wv = t >> 6;
  const int g = lane >> 4, cx = lane & 15;
  const int blk = blockIdx.x;
  const size_t c0 = (size_t)blk * 40;        // chunk-local row base

  // ---- one-time staging ----
  if (t < 48) rl[t] = (t < 40) ? (unsigned char)roles[c0 + t] : 0;
  #pragma unroll
  for (int c = 0; c < 5; ++c) {              // stage Z 40x256 fp32 -> bf16 swizzled
    const int idx = c * 256 + t;             // (row, chunk) over 40x32
    const int row = idx >> 5, ch = idx & 31;
    const float* src = Z + (c0 + row) * 256 + ch * 8;
    float4 f0 = *(const float4*)(src);
    float4 f1 = *(const float4*)(src + 4);
    union { bf16x8 v; unsigned short u[8]; } pk;
    pk.u[0] = f2bf(f0.x); pk.u[1] = f2bf(f0.y);
    pk.u[2] = f2bf(f0.z); pk.u[3] = f2bf(f0.w);
    pk.u[4] = f2bf(f1.x); pk.u[5] = f2bf(f1.y);
    pk.u[6] = f2bf(f1.z); pk.u[7] = f2bf(f1.w);
    *(bf16x8*)(lds + AS_OFF + row * 512 + ((ch ^ (row & 7)) * 16)) = pk.v;
  }
  __syncthreads();

  #pragma unroll 1
  for (int p = 0; p < 4; ++p) {
    // ======== QKV strip GEMM: 48(40 valid) x 192 (q|k|v for heads 2p,2p+1) ========
    f32x4 acc_s[3][3];
    #pragma unroll
    for (int mi = 0; mi < 3; ++mi)
      #pragma unroll
      for (int nf = 0; nf < 3; ++nf) acc_s[mi][nf] = (f32x4){0.f, 0.f, 0.f, 0.f};
    {
      const __hip_bfloat16* bptr[3];
      #pragma unroll
      for (int nf = 0; nf < 3; ++nf) {
        const int f = wv * 3 + nf;             // 0..11
        const int mf = f >> 2;                 // 0=Q,1=K,2=V
        const int ncol = p * 64 + (f & 3) * 16;
        bptr[nf] = wt + mf * 65536 + (ncol + cx) * 256 + g * 8;
      }
      #pragma unroll
      for (int kk = 0; kk < 8; ++kk) {
        bf16x8 bfr[3];
        #pragma unroll
        for (int nf = 0; nf < 3; ++nf) bfr[nf] = *(const bf16x8*)(bptr[nf] + kk * 32);
        bf16x8 afr[3];
        #pragma unroll
        for (int mi = 0; mi < 3; ++mi) {
          const int row = mi * 16 + cx;        // 0..47 (pad rows read garbage, discarded)
          const int ch = (kk * 4 + g) ^ (row & 7);
          afr[mi] = *(const bf16x8*)(lds + AS_OFF + row * 512 + ch * 16);
        }
        #pragma unroll
        for (int mi = 0; mi < 3; ++mi)
          #pragma unroll
          for (int nf = 0; nf < 3; ++nf)
            acc_s[mi][nf] = __builtin_amdgcn_mfma_f32_16x16x32_bf16(afr[mi], bfr[nf], acc_s[mi][nf], 0, 0, 0);
      }
    }
    // ======== epilogue: q|k|v -> swizzled strip (rows < 40 only) ========
    #pragma unroll
    for (int mi = 0; mi < 3; ++mi)
      #pragma unroll
      for (int nf = 0; nf < 3; ++nf) {
        const int col = wv * 48 + nf * 16 + cx;   // 0..191
        const int region = col >> 6;              // 0=q,1=k,2=v
        const int cch = (col >> 3) & 7;
        #pragma unroll
        for (int jj = 0; jj < 4; ++jj) {
          const int row = mi * 16 + g * 4 + jj;
          if (row < 40)
            *(unsigned short*)(lds + SP_OFF + row * 400 + region * 128 +
                ((cch ^ (row & 7)) * 16) + (col & 7) * 2) = f2bf(acc_s[mi][nf][jj]);
        }
      }
    __syncthreads();                               // strip ready

    // ======== VALU attention: 80 threads = 4 batches x 2 heads x 10 rows ========
    if (t < 80) {
      const int b = t / 20, hh = (t / 10) % 2, i = t % 10;
      const int h = p * 2 + hh;
      const int lrow = b * 10 + i;
      float qf[32];
      #pragma unroll
      for (int c = 0; c < 4; ++c) {
        uint4 u = *(const uint4*)(lds + SP_OFF + lrow * 400 + (((hh * 4 + c) ^ (lrow & 7)) * 16));
        qf[c*8+0] = bflo(u.x); qf[c*8+1] = bfhi(u.x);
        qf[c*8+2] = bflo(u.y); qf[c*8+3] = bfhi(u.y);
        qf[c*8+4] = bflo(u.z); qf[c*8+5] = bfhi(u.z);
        qf[c*8+6] = bflo(u.w); qf[c*8+7] = bfhi(u.w);
      }
      const int ri = rl[lrow];
      const float* brow = Bp + h * 100 + ri * 10;
      float s[10];
      #pragma unroll
      for (int j = 0; j < 10; ++j) {
        const int kr = b * 10 + j;
        const char* kbase = lds + SP_OFF + kr * 400 + 128;
        float a = 0.f;
        #pragma unroll
        for (int c = 0; c < 4; ++c) {
          uint4 u = *(const uint4*)(kbase + (((hh * 4 + c) ^ (kr & 7)) * 16));
          a += qf[c*8+0]*bflo(u.x) + qf[c*8+1]*bfhi(u.x)
             + qf[c*8+2]*bflo(u.y) + qf[c*8+3]*bfhi(u.y)
             + qf[c*8+4]*bflo(u.z) + qf[c*8+5]*bfhi(u.z)
             + qf[c*8+6]*bflo(u.w) + qf[c*8+7]*bfhi(u.w);
        }
        s[j] = a * 0.17677669529663687f + brow[rl[kr]];
      }
      float mx = s[0];
      #pragma unroll
      for (int j = 1; j < 10; ++j) mx = fmaxf(mx, s[j]);
      float sum = 0.f;
      #pragma unroll
      for (int j = 0; j < 10; ++j) { s[j] = __expf(s[j] - mx); sum += s[j]; }
      const float inv = 1.f / sum;
      float o[32];
      #pragma unroll
      for (int d = 0; d < 32; ++d) o[d] = 0.f;
      #pragma unroll
      for (int j = 0; j < 10; ++j) {
        const float pj = s[j] * inv;
        const int kr = b * 10 + j;
        const char* vbase = lds + SP_OFF + kr * 400 + 256;
        #pragma unroll
        for (int c = 0; c < 4; ++c) {
          uint4 u = *(const uint4*)(vbase + (((hh * 4 + c) ^ (kr & 7)) * 16));
          o[c*8+0] += pj * bflo(u.x); o[c*8+1] += pj * bfhi(u.x);
          o[c*8+2] += pj * bflo(u.y); o[c*8+3] += pj * bfhi(u.y);
          o[c*8+4] += pj * bflo(u.z); o[c*8+5] += pj * bfhi(u.z);
          o[c*8+6] += pj * bflo(u.w); o[c*8+7] += pj * bfhi(u.w);
        }
      }
      uint4* op = (uint4*)(attn_out + (c0 + lrow) * 256 + h * 32);   // 64 B contiguous
      #pragma unroll
      for (int c = 0; c < 4; ++c) {
        uint4 u;
        u.x = (unsigned)f2bf(o[c*8+0]) | ((unsigned)f2bf(o[c*8+1]) << 16);
        u.y = (unsigned)f2bf(o[c*8+2]) | ((unsigned)f2bf(o[c*8+3]) << 16);
        u.z = (unsigned)f2bf(o[c*8+4]) | ((unsigned)f2bf(o[c*8+5]) << 16);
        u.w = (unsigned)f2bf(o[c*8+6]) | ((unsigned)f2bf(o[c*8+7]) << 16);
        op[c] = u;
      }
    }
    __syncthreads();                               // attn done; strip free
  }
}

// ---------------- WO GEMM: out[M][256] fp32 = attn_out[M][256]bf16 @ WO ----------------
__global__ __launch_bounds__(256) void gemm_wo2_kernel(
    const __hip_bfloat16* __restrict__ A, const __hip_bfloat16* __restrict__ wt,
    float* __restrict__ C)
{
  __shared__ __align__(16) char As2[8192];
  const int t = threadIdx.x;
  const int lane = t & 63;
  const int wv = t >> 6;
  const int g = lane >> 4, cx = lane & 15;
  const size_t m0 = (size_t)blockIdx.x * 64;
  const __hip_bfloat16* WOT = wt + 3 * 65536;

  f32x4 acc[4][4];
  #pragma unroll
  for (int a = 0; a < 4; ++a)
    #pragma unroll
    for (int b = 0; b < 4; ++b) acc[a][b] = (f32x4){0.f, 0.f, 0.f, 0.f};

  #pragma unroll 1
  for (int ks = 0; ks < 4; ++ks) {
    if (ks) __syncthreads();
    #pragma unroll
    for (int c = 0; c < 2; ++c) {
      const int idx = c * 256 + t;          // 0..511 over (row, chunk)
      const int row = idx >> 3, ch = idx & 7;
      uint4 raw = *(const uint4*)(A + (m0 + row) * 256 + ks * 64 + ch * 8);
      *(uint4*)(As2 + row * 128 + ((ch ^ (row & 7)) * 16)) = raw;
    }
    __syncthreads();
    #pragma unroll
    for (int kk = 0; kk < 2; ++kk) {
      bf16x8 bfr[4];
      #pragma unroll
      for (int nf = 0; nf < 4; ++nf) {
        const int n = wv * 64 + nf * 16 + cx;
        bfr[nf] = *(const bf16x8*)(WOT + n * 256 + ks * 64 + kk * 32 + g * 8);
      }
      bf16x8 afr[4];
      #pragma unroll
      for (int mi = 0; mi < 4; ++mi) {
        const int row = mi * 16 + cx;
        const int ch = (kk * 4 + g) ^ (row & 7);
        afr[mi] = *(const bf16x8*)(As2 + row * 128 + ch * 16);
      }
      #pragma unroll
      for (int mi = 0; mi < 4; ++mi)
        #pragma unroll
        for (int nf = 0; nf < 4; ++nf)
          acc[mi][nf] = __builtin_amdgcn_mfma_f32_16x16x32_bf16(afr[mi], bfr[nf], acc[mi][nf], 0, 0, 0);
    }
  }
  #pragma unroll
  for (int mi = 0; mi < 4; ++mi)
    #pragma unroll
    for (int nf = 0; nf < 4; ++nf)
      #pragma unroll
      for (int jj = 0; jj < 4; ++jj) {
        const size_t row = m0 + mi * 16 + g * 4 + jj;
        const int col = wv * 64 + nf * 16 + cx;
        C[row * 256 + col] = acc[mi][nf][jj];
      }
}

extern "C" void kernel_launch(void* const* d_in, const int* in_sizes, int n_in,
                              void* d_out, int out_size, void* d_ws, size_t ws_size,
                              hipStream_t stream)
{
  const float* Z     = (const float*)d_in[0];
  const int*   roles = (const int*)d_in[1];
  const float* WQ    = (const float*)d_in[2];
  const float* WK    = (const float*)d_in[3];
  const float* WV    = (const float*)d_in[4];
  const float* WO    = (const float*)d_in[5];
  const float* Bp    = (const float*)d_in[6];
  float* out = (float*)d_out;

  const long M = 163840;                         // 16384 batches * 10 rows
  char* ws = (char*)d_ws;
  __hip_bfloat16* wt = (__hip_bfloat16*)ws;
  const size_t WT_BYTES = 4u * 256u * 256u * 2u; // 512 KiB
  __hip_bfloat16* attn_ws = (__hip_bfloat16*)(ws + WT_BYTES);

  // chunking (attn_out row = 512 B); chunk multiple of 320 = lcm(40, 64)
  size_t avail = (ws_size > WT_BYTES) ? (ws_size - WT_BYTES) : 0;
  long rows_fit = (long)(avail / 512);
  long chunk = (rows_fit / 320) * 320;
  if (chunk > M) chunk = M;
  if (chunk < 320) chunk = 320;

  prep_wt_kernel<<<256, 256, 0, stream>>>(WQ, WK, WV, WO, wt);

  for (long r0 = 0; r0 < M; r0 += chunk) {
    long rows = M - r0;
    if (rows > chunk) rows = chunk;
    fused_qkv_attn_kernel<<<(int)(rows / 40), 256, 0, stream>>>(
        Z + r0 * 256, wt, roles + r0, Bp, attn_ws);
    gemm_wo2_kernel<<<(int)(rows / 64), 256, 0, stream>>>(
        attn_ws, wt, out + r0 * 256);
  }
}